// Round 18
// baseline (44.732 us; speedup 1.0000x reference)
//
#include <hip/hip_runtime.h>
#include <math.h>

#define BB 16
#define CC 256
#define HH 64
#define WW 32
#define NN (HH*WW)            // 2048
#define NEGC (-9e15f)
#define CPAD 136              // bf16 elems per LDS row: 272B stride, 16B-aligned rows

typedef __attribute__((ext_vector_type(8))) short bf16x8;
typedef __attribute__((ext_vector_type(4))) float f32x4;

// scratch (capture-safe device globals; fully rewritten before any read each call)
__device__ float g_wlo[BB*CC];                    // channel-softmax weight on c-1
__device__ float g_whi[BB*CC];                    // channel-softmax weight on c+1
__device__ unsigned short g_asb[(size_t)BB*NN*64]; // as[b][p][k] (bf16): alpha 0..31, sigma 32..63
__device__ float g_part[BB*32*256];               // per-(b,ptile) pair-dot partials
__device__ unsigned short g_w8b[(size_t)BB*NN*8]; // spatial softmax weights (bf16)

__device__ __forceinline__ unsigned short f2bf(float f) {   // RNE f32->bf16
    unsigned int u = __float_as_uint(f);
    u += 0x7FFFu + ((u >> 16) & 1u);
    return (unsigned short)(u >> 16);
}
__device__ __forceinline__ float bf2f(unsigned short s) {
    return __uint_as_float(((unsigned int)s) << 16);
}
__device__ __forceinline__ float bflo(unsigned int u) {   // elem 2i   (bits 0-15)
    return __uint_as_float(u << 16);
}
__device__ __forceinline__ float bfhi(unsigned int u) {   // elem 2i+1 (bits 16-31)
    return __uint_as_float(u & 0xFFFF0000u);
}

// ============ K1: alpha/sigma GEMM via MFMA bf16 + fp32 pair dots ============
// (round-17 version, unchanged — control)
__global__ __launch_bounds__(256) void k_gemm(
        const float* __restrict__ x,
        const float* __restrict__ wa, const float* __restrict__ ga,
        const float* __restrict__ va, const float* __restrict__ ba,
        const float* __restrict__ ma, const float* __restrict__ wsig,
        const float* __restrict__ gs, const float* __restrict__ vs,
        const float* __restrict__ bs, const float* __restrict__ ms) {
    __shared__ unsigned short xbuf[64*CPAD];   // [p][c_local] bf16
    __shared__ unsigned short wbuf[64*CPAD];   // [k][c_local] bf16 (BN-folded)
    int blk = blockIdx.x;
    int b = blk >> 5, tile = blk & 31;
    int t = threadIdx.x;
    int p0 = tile*64;
    const float* xb = x + (size_t)b*CC*NN + p0;

    int kw = t >> 2, sub = t & 3;
    const float* wrow; float g_, v_;
    if (kw < 32) { g_ = ga[kw]; v_ = va[kw]; wrow = wa + kw*CC; }
    else         { g_ = gs[kw-32]; v_ = vs[kw-32]; wrow = wsig + (kw-32)*CC; }
    float invk = g_ * rsqrtf(v_ + 1e-5f);

    int g = t >> 4, q = t & 15;
    int wv_ = t >> 6;
    int lane = t & 63;
    int pcol = lane & 15, grp = lane >> 4;

    f32x4 acc[4];
    #pragma unroll
    for (int i = 0; i < 4; ++i) acc[i] = (f32x4){0.f, 0.f, 0.f, 0.f};

    #pragma unroll
    for (int h = 0; h < 2; ++h) {
        if (h) __syncthreads();
        float pp[8];
        #pragma unroll
        for (int i = 0; i < 8; ++i) pp[i] = 0.f;
        float4 prev = make_float4(0.f, 0.f, 0.f, 0.f);
        #pragma unroll
        for (int i = 0; i <= 8; ++i) {
            int c = h*128 + g*8 + i;
            float4 v = make_float4(0.f, 0.f, 0.f, 0.f);
            if (c < CC) v = *(const float4*)(xb + (size_t)c*NN + q*4);
            if (i < 8) {
                int cl = g*8 + i;
                xbuf[(q*4+0)*CPAD + cl] = f2bf(v.x);
                xbuf[(q*4+1)*CPAD + cl] = f2bf(v.y);
                xbuf[(q*4+2)*CPAD + cl] = f2bf(v.z);
                xbuf[(q*4+3)*CPAD + cl] = f2bf(v.w);
            }
            if (i > 0) {
                pp[i-1] = fmaf(prev.x, v.x, pp[i-1]);
                pp[i-1] = fmaf(prev.y, v.y, pp[i-1]);
                pp[i-1] = fmaf(prev.z, v.z, pp[i-1]);
                pp[i-1] = fmaf(prev.w, v.w, pp[i-1]);
            }
            prev = v;
        }
        float myv = 0.f;
        #pragma unroll
        for (int i = 0; i < 8; ++i) {
            float r = pp[i];
            r += __shfl_xor(r, 1, 64);
            r += __shfl_xor(r, 2, 64);
            r += __shfl_xor(r, 4, 64);
            r += __shfl_xor(r, 8, 64);
            if (q == i) myv = r;
        }
        if (q < 8) {
            int c = h*128 + g*8 + q;
            g_part[(b*32 + tile)*256 + c] = myv;
        }
        #pragma unroll
        for (int m = 0; m < 8; ++m) {
            int cl = sub*32 + m*4;
            float4 w4 = *(const float4*)(wrow + h*128 + cl);
            unsigned int pk0 = (unsigned int)f2bf(w4.x*invk) |
                               ((unsigned int)f2bf(w4.y*invk) << 16);
            unsigned int pk1 = (unsigned int)f2bf(w4.z*invk) |
                               ((unsigned int)f2bf(w4.w*invk) << 16);
            *(unsigned int*)&wbuf[kw*CPAD + cl]     = pk0;
            *(unsigned int*)&wbuf[kw*CPAD + cl + 2] = pk1;
        }
        __syncthreads();
        #pragma unroll
        for (int cs = 0; cs < 4; ++cs) {
            int c_off = cs*32 + grp*8;
            bf16x8 bfrag = *(const bf16x8*)&xbuf[(wv_*16 + pcol)*CPAD + c_off];
            #pragma unroll
            for (int kt = 0; kt < 4; ++kt) {
                bf16x8 afrag = *(const bf16x8*)&wbuf[(kt*16 + pcol)*CPAD + c_off];
                acc[kt] = __builtin_amdgcn_mfma_f32_16x16x32_bf16(afrag, bfrag, acc[kt], 0, 0, 0);
            }
        }
    }

    // epilogue: bias + relu in fp32, store bf16 pairs (uint2, 8B/lane)
    #pragma unroll
    for (int kt = 0; kt < 4; ++kt) {
        int k0 = kt*16 + grp*4;
        float4 gv, vv, bv, mv;
        if (k0 < 32) {
            gv = *(const float4*)(ga + k0); vv = *(const float4*)(va + k0);
            bv = *(const float4*)(ba + k0); mv = *(const float4*)(ma + k0);
        } else {
            gv = *(const float4*)(gs + k0-32); vv = *(const float4*)(vs + k0-32);
            bv = *(const float4*)(bs + k0-32); mv = *(const float4*)(ms + k0-32);
        }
        float i0 = gv.x * rsqrtf(vv.x + 1e-5f);
        float i1 = gv.y * rsqrtf(vv.y + 1e-5f);
        float i2 = gv.z * rsqrtf(vv.z + 1e-5f);
        float i3 = gv.w * rsqrtf(vv.w + 1e-5f);
        float rx = fmaxf(acc[kt][0] + (bv.x - mv.x*i0), 0.f);
        float ry = fmaxf(acc[kt][1] + (bv.y - mv.y*i1), 0.f);
        float rz = fmaxf(acc[kt][2] + (bv.z - mv.z*i2), 0.f);
        float rw = fmaxf(acc[kt][3] + (bv.w - mv.w*i3), 0.f);
        uint2 pk;
        pk.x = (unsigned int)f2bf(rx) | ((unsigned int)f2bf(ry) << 16);
        pk.y = (unsigned int)f2bf(rz) | ((unsigned int)f2bf(rw) << 16);
        *(uint2*)&g_asb[(((size_t)(b*NN + p0 + wv_*16 + pcol)) << 6) + k0] = pk;
    }
}

// ---------------- K2: spatial softmax weights (bf16 in/out) + channel softmax ----------------
// (round-17 version, unchanged — control)
#define WBLK (BB*NN/32)   // 1024: each block does 32 positions x 8 neighbors
__global__ __launch_bounds__(256) void k_wc() {
    __shared__ float lds_s[256];
    int blk = blockIdx.x;
    int t = threadIdx.x;
    if (blk < WBLK) {
        int pos_local = t >> 3, j = t & 7;
        int idx = blk*32 + pos_local;
        int b = idx >> 11, p = idx & (NN-1);
        int gr = p >> 5, col = p & 31;
        const int dy[8] = {-1,-1,-1, 0,0, 1,1,1};
        const int dx[8] = {-1, 0, 1,-1,1,-1,0,1};
        int qr = gr + dy[j], qc = col + dx[j];
        bool ok = (qr >= 0) && (qr < HH) && (qc >= 0) && (qc < WW);
        int q = ok ? (qr*WW + qc) : p;
        const unsigned int* ap = (const unsigned int*)(g_asb + (((size_t)b*NN + p) << 6));
        const unsigned int* sp = (const unsigned int*)(g_asb + (((size_t)b*NN + q) << 6) + 32);
        float d = 0.f;
        #pragma unroll
        for (int k4 = 0; k4 < 4; ++k4) {
            uint4 ua = *(const uint4*)(ap + k4*4);
            uint4 us = *(const uint4*)(sp + k4*4);
            d = fmaf(bflo(ua.x), bflo(us.x), d); d = fmaf(bfhi(ua.x), bfhi(us.x), d);
            d = fmaf(bflo(ua.y), bflo(us.y), d); d = fmaf(bfhi(ua.y), bfhi(us.y), d);
            d = fmaf(bflo(ua.z), bflo(us.z), d); d = fmaf(bfhi(ua.z), bfhi(us.z), d);
            d = fmaf(bflo(ua.w), bflo(us.w), d); d = fmaf(bfhi(ua.w), bfhi(us.w), d);
        }
        float logit = ok ? d : NEGC;
        float m = logit;                       // max over the 8-lane neighbor group
        m = fmaxf(m, __shfl_xor(m, 1, 64));
        m = fmaxf(m, __shfl_xor(m, 2, 64));
        m = fmaxf(m, __shfl_xor(m, 4, 64));
        float e = expf(logit - m);
        float s8 = e;
        s8 += __shfl_xor(s8, 1, 64);
        s8 += __shfl_xor(s8, 2, 64);
        s8 += __shfl_xor(s8, 4, 64);
        g_w8b[(size_t)idx*8 + j] = f2bf(e / s8);
    } else {
        int b = blk - WBLK;
        float s = 0.f;
        #pragma unroll 8
        for (int tile = 0; tile < 32; ++tile) s += g_part[(b*32 + tile)*256 + t];
        lds_s[t] = s;                          // pair-dot for pair (t, t+1)
        __syncthreads();
        int c = t;
        float glo = (c > 0)      ? lds_s[c-1] : NEGC;
        float ghi = (c < CC - 1) ? lds_s[c]   : NEGC;
        float m = fmaxf(glo, ghi);
        float elo = expf(glo - m), ehi = expf(ghi - m);
        float inv = 1.0f / (elo + ehi);
        g_wlo[b*CC + c] = elo * inv;
        g_whi[b*CC + c] = ehi * inv;
    }
}

// ---------------- K3: stencil + channel blend + elu + mix (bf16 LDS halo tile) ----
// grid: 1024 blocks = b(16) x strip(8 rows)(8) x cgroup(32 ch)(8); 512 threads = 8 waves,
// each wave owns 4 channels.  LDS: wtab 9.2KB + xt 27.2KB = 36.4KB -> 4 blocks/CU
// = 32 waves/CU (was 24); halo amplification 1.0625x (was 1.125x); wtab duplication
// halved.  Inner lane mapping identical to round 16/17.
__global__ __launch_bounds__(512) void k_main(const float* __restrict__ x,
                                              const float* __restrict__ gama_p,
                                              float* __restrict__ out) {
    __shared__ float wtab[256][9];
    __shared__ unsigned short xt[34*10*40];   // bf16 halo tile: 34 ch-slots x 10 rows x 40 stride
    int blk = blockIdx.x;
    int b = blk >> 6;
    int strip = (blk >> 3) & 7;
    int cg = blk & 7;
    int t = threadIdx.x;
    int r0 = strip << 3;
    int c0 = cg << 5;
    const float* xb = x + (size_t)b*CC*NN;

    {   // stage softmax weights: 512 threads x 1 ushort4 each (256 pos x 2 halves)
        int pos = t >> 1, half = t & 1;
        ushort4 w = *(const ushort4*)(g_w8b + ((size_t)(b*NN + r0*WW + pos))*8 + half*4);
        int j0 = half*4;
        wtab[pos][j0+0] = bf2f(w.x);
        wtab[pos][j0+1] = bf2f(w.y);
        wtab[pos][j0+2] = bf2f(w.z);
        wtab[pos][j0+3] = bf2f(w.w);
    }
    // stage x halo tile (bf16): 34*10 = 340 row-segments x 8 quads = 2720 ushort4
    for (int i = t; i < 2720; i += 512) {
        int seg = i >> 3, quad = i & 7;
        int ch_s = seg / 10, r_s = seg - ch_s*10;
        int gc = c0 - 1 + ch_s;  gc = (gc < 0) ? 0 : (gc > CC-1 ? CC-1 : gc);
        int gr = r0 - 1 + r_s;   gr = (gr < 0) ? 0 : (gr > HH-1 ? HH-1 : gr);
        float4 v = *(const float4*)(xb + (size_t)gc*NN + gr*WW + quad*4);
        ushort4 u;
        u.x = f2bf(v.x); u.y = f2bf(v.y); u.z = f2bf(v.z); u.w = f2bf(v.w);
        *(ushort4*)&xt[(ch_s*10 + r_s)*40 + quad*4] = u;
    }
    __syncthreads();

    int wave = __builtin_amdgcn_readfirstlane(t >> 6);   // 0..7
    int lane = t & 63;
    int lrow = lane >> 3;            // row within strip
    int lcq  = (lane & 7) << 2;      // column quad start
    float wq[4][8];
    #pragma unroll
    for (int i = 0; i < 4; ++i) {
        int prow = lrow*32 + lcq + i;
        #pragma unroll
        for (int j = 0; j < 8; ++j) wq[i][j] = wtab[prow][j];
    }
    float gama = gama_p[0];
    int cw0 = wave*4;                // this wave's first channel offset (slot cw0+1)
    int pbase = r0*WW + lane*4;      // for the global store
    float* ob = out + (size_t)b*CC*NN;

    float pm1[4], o0[4];
    {
        ushort4 uv = *(const ushort4*)&xt[((cw0+0)*10 + (lrow+1))*40 + lcq];   // slot c0-1+cw0
        pm1[0]=bf2f(uv.x); pm1[1]=bf2f(uv.y); pm1[2]=bf2f(uv.z); pm1[3]=bf2f(uv.w);
        ushort4 uw = *(const ushort4*)&xt[((cw0+1)*10 + (lrow+1))*40 + lcq];   // own channel
        o0[0]=bf2f(uw.x); o0[1]=bf2f(uw.y); o0[2]=bf2f(uw.z); o0[3]=bf2f(uw.w);
    }
    #pragma unroll
    for (int cc = 0; cc < 4; ++cc) {
        int c = c0 + cw0 + cc;
        int slot = cw0 + 1 + cc;
        ushort4 u1 = *(const ushort4*)&xt[((slot+1)*10 + (lrow+1))*40 + lcq];  // c+1 (clamped)
        float p1[4] = {bf2f(u1.x), bf2f(u1.y), bf2f(u1.z), bf2f(u1.w)};
        ushort4 ua = *(const ushort4*)&xt[( slot   *10 + lrow    )*40 + lcq];  // row above
        float aw[4] = {bf2f(ua.x), bf2f(ua.y), bf2f(ua.z), bf2f(ua.w)};
        ushort4 ub = *(const ushort4*)&xt[( slot   *10 + lrow + 2)*40 + lcq];  // row below
        float bw[4] = {bf2f(ub.x), bf2f(ub.y), bf2f(ub.z), bf2f(ub.w)};
        float al  = __shfl_up(aw[3], 1);
        float ar  = __shfl_down(aw[0], 1);
        float ol  = __shfl_up(o0[3], 1);
        float orr = __shfl_down(o0[0], 1);
        float bl  = __shfl_up(bw[3], 1);
        float br  = __shfl_down(bw[0], 1);
        float wlo_c = g_wlo[b*CC + c];
        float whi_c = g_whi[b*CC + c];
        float res[4];
        #pragma unroll
        for (int i = 0; i < 4; ++i) {
            float ul = (i == 0) ? al  : aw[i-1];
            float uu = aw[i];
            float ur = (i == 3) ? ar  : aw[i+1];
            float ll = (i == 0) ? ol  : o0[i-1];
            float rr = (i == 3) ? orr : o0[i+1];
            float dl = (i == 0) ? bl  : bw[i-1];
            float dd = bw[i];
            float dr = (i == 3) ? br  : bw[i+1];
            float hs = wq[i][0]*ul + wq[i][1]*uu + wq[i][2]*ur
                     + wq[i][3]*ll + wq[i][4]*rr
                     + wq[i][5]*dl + wq[i][6]*dd + wq[i][7]*dr;
            float hp = wlo_c*pm1[i] + whi_c*p1[i];
            float h  = hs + hp;
            float el = (h > 0.f) ? h : expm1f(h);
            res[i] = o0[i] + gama*(el - o0[i]);       // (1-g)x + g*h'
        }
        *(float4*)(ob + (size_t)c*NN + pbase) = make_float4(res[0], res[1], res[2], res[3]);
        #pragma unroll
        for (int i = 0; i < 4; ++i) { pm1[i] = o0[i]; o0[i] = p1[i]; }
    }
}

extern "C" void kernel_launch(void* const* d_in, const int* in_sizes, int n_in,
                              void* d_out, int out_size, void* d_ws, size_t ws_size,
                              hipStream_t stream) {
    const float* x    = (const float*)d_in[0];
    const float* wa   = (const float*)d_in[1];
    const float* ga   = (const float*)d_in[2];
    const float* ba   = (const float*)d_in[3];
    const float* ma   = (const float*)d_in[4];
    const float* va   = (const float*)d_in[5];
    const float* wsig = (const float*)d_in[6];
    const float* gs   = (const float*)d_in[7];
    const float* bs   = (const float*)d_in[8];
    const float* ms   = (const float*)d_in[9];
    const float* vs   = (const float*)d_in[10];
    const float* gama = (const float*)d_in[11];
    float* out = (float*)d_out;

    hipLaunchKernelGGL(k_gemm, dim3(512),      dim3(256), 0, stream,
                       x, wa, ga, va, ba, ma, wsig, gs, vs, bs, ms);
    hipLaunchKernelGGL(k_wc,   dim3(WBLK+BB),  dim3(256), 0, stream);
    hipLaunchKernelGGL(k_main, dim3(1024),     dim3(512), 0, stream, x, gama, out);
}

// Round 19
// 43.786 us; speedup vs baseline: 1.0216x; 1.0216x over previous
//
#include <hip/hip_runtime.h>
#include <math.h>

#define BB 16
#define CC 256
#define HH 64
#define WW 32
#define NN (HH*WW)            // 2048
#define NEGC (-9e15f)
#define CPAD 136              // bf16 elems per LDS row: 272B stride, 16B-aligned rows

typedef __attribute__((ext_vector_type(8))) short bf16x8;
typedef __attribute__((ext_vector_type(4))) float f32x4;

// scratch (capture-safe device globals; fully rewritten before any read each call)
__device__ float g_wlo[BB*CC];                    // channel-softmax weight on c-1
__device__ float g_whi[BB*CC];                    // channel-softmax weight on c+1
__device__ unsigned short g_asb[(size_t)BB*NN*64]; // as[b][p][k] (bf16): alpha 0..31, sigma 32..63
__device__ float g_part[BB*32*256];               // per-(b,ptile) pair-dot partials
__device__ unsigned short g_w8b[(size_t)BB*NN*8]; // spatial softmax weights (bf16)

__device__ __forceinline__ unsigned short f2bf(float f) {   // RNE f32->bf16
    unsigned int u = __float_as_uint(f);
    u += 0x7FFFu + ((u >> 16) & 1u);
    return (unsigned short)(u >> 16);
}
__device__ __forceinline__ float bf2f(unsigned short s) {
    return __uint_as_float(((unsigned int)s) << 16);
}
__device__ __forceinline__ float bflo(unsigned int u) {   // elem 2i   (bits 0-15)
    return __uint_as_float(u << 16);
}
__device__ __forceinline__ float bfhi(unsigned int u) {   // elem 2i+1 (bits 16-31)
    return __uint_as_float(u & 0xFFFF0000u);
}

// ============ K1: alpha/sigma GEMM via MFMA bf16 + fp32 pair dots ============
// g_asb[b][p][k] = bf16(relu(bias[k] + sum_c (W[k][c]*inv[k]) * x[b][c][p]))
// g_part[b][ptile][c] = fp32 pair dots from global regs.
__global__ __launch_bounds__(256) void k_gemm(
        const float* __restrict__ x,
        const float* __restrict__ wa, const float* __restrict__ ga,
        const float* __restrict__ va, const float* __restrict__ ba,
        const float* __restrict__ ma, const float* __restrict__ wsig,
        const float* __restrict__ gs, const float* __restrict__ vs,
        const float* __restrict__ bs, const float* __restrict__ ms) {
    __shared__ unsigned short xbuf[64*CPAD];   // [p][c_local] bf16
    __shared__ unsigned short wbuf[64*CPAD];   // [k][c_local] bf16 (BN-folded)
    int blk = blockIdx.x;
    int b = blk >> 5, tile = blk & 31;
    int t = threadIdx.x;
    int p0 = tile*64;
    const float* xb = x + (size_t)b*CC*NN + p0;

    int kw = t >> 2, sub = t & 3;
    const float* wrow; float g_, v_;
    if (kw < 32) { g_ = ga[kw]; v_ = va[kw]; wrow = wa + kw*CC; }
    else         { g_ = gs[kw-32]; v_ = vs[kw-32]; wrow = wsig + (kw-32)*CC; }
    float invk = g_ * rsqrtf(v_ + 1e-5f);

    int g = t >> 4, q = t & 15;
    int wv_ = t >> 6;
    int lane = t & 63;
    int pcol = lane & 15, grp = lane >> 4;

    f32x4 acc[4];
    #pragma unroll
    for (int i = 0; i < 4; ++i) acc[i] = (f32x4){0.f, 0.f, 0.f, 0.f};

    #pragma unroll
    for (int h = 0; h < 2; ++h) {
        if (h) __syncthreads();
        float pp[8];
        #pragma unroll
        for (int i = 0; i < 8; ++i) pp[i] = 0.f;
        float4 prev = make_float4(0.f, 0.f, 0.f, 0.f);
        #pragma unroll
        for (int i = 0; i <= 8; ++i) {
            int c = h*128 + g*8 + i;
            float4 v = make_float4(0.f, 0.f, 0.f, 0.f);
            if (c < CC) v = *(const float4*)(xb + (size_t)c*NN + q*4);
            if (i < 8) {
                int cl = g*8 + i;
                xbuf[(q*4+0)*CPAD + cl] = f2bf(v.x);
                xbuf[(q*4+1)*CPAD + cl] = f2bf(v.y);
                xbuf[(q*4+2)*CPAD + cl] = f2bf(v.z);
                xbuf[(q*4+3)*CPAD + cl] = f2bf(v.w);
            }
            if (i > 0) {
                pp[i-1] = fmaf(prev.x, v.x, pp[i-1]);
                pp[i-1] = fmaf(prev.y, v.y, pp[i-1]);
                pp[i-1] = fmaf(prev.z, v.z, pp[i-1]);
                pp[i-1] = fmaf(prev.w, v.w, pp[i-1]);
            }
            prev = v;
        }
        float myv = 0.f;
        #pragma unroll
        for (int i = 0; i < 8; ++i) {
            float r = pp[i];
            r += __shfl_xor(r, 1, 64);
            r += __shfl_xor(r, 2, 64);
            r += __shfl_xor(r, 4, 64);
            r += __shfl_xor(r, 8, 64);
            if (q == i) myv = r;
        }
        if (q < 8) {
            int c = h*128 + g*8 + q;
            g_part[(b*32 + tile)*256 + c] = myv;
        }
        #pragma unroll
        for (int m = 0; m < 8; ++m) {
            int cl = sub*32 + m*4;
            float4 w4 = *(const float4*)(wrow + h*128 + cl);
            unsigned int pk0 = (unsigned int)f2bf(w4.x*invk) |
                               ((unsigned int)f2bf(w4.y*invk) << 16);
            unsigned int pk1 = (unsigned int)f2bf(w4.z*invk) |
                               ((unsigned int)f2bf(w4.w*invk) << 16);
            *(unsigned int*)&wbuf[kw*CPAD + cl]     = pk0;
            *(unsigned int*)&wbuf[kw*CPAD + cl + 2] = pk1;
        }
        __syncthreads();
        #pragma unroll
        for (int cs = 0; cs < 4; ++cs) {
            int c_off = cs*32 + grp*8;
            bf16x8 bfrag = *(const bf16x8*)&xbuf[(wv_*16 + pcol)*CPAD + c_off];
            #pragma unroll
            for (int kt = 0; kt < 4; ++kt) {
                bf16x8 afrag = *(const bf16x8*)&wbuf[(kt*16 + pcol)*CPAD + c_off];
                acc[kt] = __builtin_amdgcn_mfma_f32_16x16x32_bf16(afrag, bfrag, acc[kt], 0, 0, 0);
            }
        }
    }

    // epilogue: bias + relu in fp32, store bf16 pairs (uint2, 8B/lane)
    #pragma unroll
    for (int kt = 0; kt < 4; ++kt) {
        int k0 = kt*16 + grp*4;
        float4 gv, vv, bv, mv;
        if (k0 < 32) {
            gv = *(const float4*)(ga + k0); vv = *(const float4*)(va + k0);
            bv = *(const float4*)(ba + k0); mv = *(const float4*)(ma + k0);
        } else {
            gv = *(const float4*)(gs + k0-32); vv = *(const float4*)(vs + k0-32);
            bv = *(const float4*)(bs + k0-32); mv = *(const float4*)(ms + k0-32);
        }
        float i0 = gv.x * rsqrtf(vv.x + 1e-5f);
        float i1 = gv.y * rsqrtf(vv.y + 1e-5f);
        float i2 = gv.z * rsqrtf(vv.z + 1e-5f);
        float i3 = gv.w * rsqrtf(vv.w + 1e-5f);
        float rx = fmaxf(acc[kt][0] + (bv.x - mv.x*i0), 0.f);
        float ry = fmaxf(acc[kt][1] + (bv.y - mv.y*i1), 0.f);
        float rz = fmaxf(acc[kt][2] + (bv.z - mv.z*i2), 0.f);
        float rw = fmaxf(acc[kt][3] + (bv.w - mv.w*i3), 0.f);
        uint2 pk;
        pk.x = (unsigned int)f2bf(rx) | ((unsigned int)f2bf(ry) << 16);
        pk.y = (unsigned int)f2bf(rz) | ((unsigned int)f2bf(rw) << 16);
        *(uint2*)&g_asb[(((size_t)(b*NN + p0 + wv_*16 + pcol)) << 6) + k0] = pk;
    }
}

// ---------------- K2: spatial softmax weights (bf16 in/out) + channel softmax ----------------
#define WBLK (BB*NN/32)   // 1024: each block does 32 positions x 8 neighbors
__global__ __launch_bounds__(256) void k_wc() {
    __shared__ float lds_s[256];
    int blk = blockIdx.x;
    int t = threadIdx.x;
    if (blk < WBLK) {
        int pos_local = t >> 3, j = t & 7;
        int idx = blk*32 + pos_local;
        int b = idx >> 11, p = idx & (NN-1);
        int gr = p >> 5, col = p & 31;
        const int dy[8] = {-1,-1,-1, 0,0, 1,1,1};
        const int dx[8] = {-1, 0, 1,-1,1,-1,0,1};
        int qr = gr + dy[j], qc = col + dx[j];
        bool ok = (qr >= 0) && (qr < HH) && (qc >= 0) && (qc < WW);
        int q = ok ? (qr*WW + qc) : p;
        const unsigned int* ap = (const unsigned int*)(g_asb + (((size_t)b*NN + p) << 6));
        const unsigned int* sp = (const unsigned int*)(g_asb + (((size_t)b*NN + q) << 6) + 32);
        float d = 0.f;
        #pragma unroll
        for (int k4 = 0; k4 < 4; ++k4) {
            uint4 ua = *(const uint4*)(ap + k4*4);
            uint4 us = *(const uint4*)(sp + k4*4);
            d = fmaf(bflo(ua.x), bflo(us.x), d); d = fmaf(bfhi(ua.x), bfhi(us.x), d);
            d = fmaf(bflo(ua.y), bflo(us.y), d); d = fmaf(bfhi(ua.y), bfhi(us.y), d);
            d = fmaf(bflo(ua.z), bflo(us.z), d); d = fmaf(bfhi(ua.z), bfhi(us.z), d);
            d = fmaf(bflo(ua.w), bflo(us.w), d); d = fmaf(bfhi(ua.w), bfhi(us.w), d);
        }
        float logit = ok ? d : NEGC;
        float m = logit;                       // max over the 8-lane neighbor group
        m = fmaxf(m, __shfl_xor(m, 1, 64));
        m = fmaxf(m, __shfl_xor(m, 2, 64));
        m = fmaxf(m, __shfl_xor(m, 4, 64));
        float e = expf(logit - m);
        float s8 = e;
        s8 += __shfl_xor(s8, 1, 64);
        s8 += __shfl_xor(s8, 2, 64);
        s8 += __shfl_xor(s8, 4, 64);
        g_w8b[(size_t)idx*8 + j] = f2bf(e / s8);
    } else {
        int b = blk - WBLK;
        float s = 0.f;
        #pragma unroll 8
        for (int tile = 0; tile < 32; ++tile) s += g_part[(b*32 + tile)*256 + t];
        lds_s[t] = s;                          // pair-dot for pair (t, t+1)
        __syncthreads();
        int c = t;
        float glo = (c > 0)      ? lds_s[c-1] : NEGC;
        float ghi = (c < CC - 1) ? lds_s[c]   : NEGC;
        float m = fmaxf(glo, ghi);
        float elo = expf(glo - m), ehi = expf(ghi - m);
        float inv = 1.0f / (elo + ehi);
        g_wlo[b*CC + c] = elo * inv;
        g_whi[b*CC + c] = ehi * inv;
    }
}

// ---------------- K3: stencil + channel blend + elu + mix (bf16 LDS halo tile) ----
// grid: 2048 blocks = b(16) x strip(8 rows)(8) x cgroup(16 ch)(16); 4 waves = 4 ch each
// xt stored bf16 (row stride 40 ushorts = 80B, 8B-aligned); all math fp32.
__global__ __launch_bounds__(256) void k_main(const float* __restrict__ x,
                                              const float* __restrict__ gama_p,
                                              float* __restrict__ out) {
    __shared__ float wtab[256][9];
    __shared__ unsigned short xt[18*10*40];   // bf16 halo tile
    int blk = blockIdx.x;
    int b = blk >> 7;
    int strip = (blk >> 4) & 7;
    int cg = blk & 15;
    int t = threadIdx.x;
    int r0 = strip << 3;
    int c0 = cg << 4;
    const float* xb = x + (size_t)b*CC*NN;

    {   // stage softmax weights (one thread per position), bf16 -> fp32
        const ushort4* wsrc = (const ushort4*)(g_w8b + ((size_t)(b*NN + r0*WW + t))*8);
        ushort4 w0 = wsrc[0], w1 = wsrc[1];
        wtab[t][0]=bf2f(w0.x); wtab[t][1]=bf2f(w0.y); wtab[t][2]=bf2f(w0.z); wtab[t][3]=bf2f(w0.w);
        wtab[t][4]=bf2f(w1.x); wtab[t][5]=bf2f(w1.y); wtab[t][6]=bf2f(w1.z); wtab[t][7]=bf2f(w1.w);
    }
    // stage x halo tile (bf16): 18*10 = 180 row-segments x 8 quads = 1440 float4
    for (int i = t; i < 1440; i += 256) {
        int seg = i >> 3, quad = i & 7;
        int ch_s = seg / 10, r_s = seg - ch_s*10;
        int gc = c0 - 1 + ch_s;  gc = (gc < 0) ? 0 : (gc > CC-1 ? CC-1 : gc);
        int gr = r0 - 1 + r_s;   gr = (gr < 0) ? 0 : (gr > HH-1 ? HH-1 : gr);
        float4 v = *(const float4*)(xb + (size_t)gc*NN + gr*WW + quad*4);
        ushort4 u;
        u.x = f2bf(v.x); u.y = f2bf(v.y); u.z = f2bf(v.z); u.w = f2bf(v.w);
        *(ushort4*)&xt[(ch_s*10 + r_s)*40 + quad*4] = u;
    }
    __syncthreads();

    int wave = __builtin_amdgcn_readfirstlane(t >> 6);
    int lane = t & 63;
    int lrow = lane >> 3;            // row within strip
    int lcq  = (lane & 7) << 2;      // column quad start
    float wq[4][8];
    #pragma unroll
    for (int i = 0; i < 4; ++i) {
        int prow = lrow*32 + lcq + i;
        #pragma unroll
        for (int j = 0; j < 8; ++j) wq[i][j] = wtab[prow][j];
    }
    float gama = gama_p[0];
    int cw0 = wave*4;                // this wave's first channel (slot cw0+1)
    int pbase = r0*WW + lane*4;      // for the global store
    float* ob = out + (size_t)b*CC*NN;

    float pm1[4], o0[4];
    {
        ushort4 uv = *(const ushort4*)&xt[((cw0+0)*10 + (lrow+1))*40 + lcq];   // slot c0-1+cw0
        pm1[0]=bf2f(uv.x); pm1[1]=bf2f(uv.y); pm1[2]=bf2f(uv.z); pm1[3]=bf2f(uv.w);
        ushort4 uw = *(const ushort4*)&xt[((cw0+1)*10 + (lrow+1))*40 + lcq];   // own channel
        o0[0]=bf2f(uw.x); o0[1]=bf2f(uw.y); o0[2]=bf2f(uw.z); o0[3]=bf2f(uw.w);
    }
    #pragma unroll
    for (int cc = 0; cc < 4; ++cc) {
        int c = c0 + cw0 + cc;
        int slot = cw0 + 1 + cc;
        ushort4 u1 = *(const ushort4*)&xt[((slot+1)*10 + (lrow+1))*40 + lcq];  // c+1 (clamped)
        float p1[4] = {bf2f(u1.x), bf2f(u1.y), bf2f(u1.z), bf2f(u1.w)};
        ushort4 ua = *(const ushort4*)&xt[( slot   *10 + lrow    )*40 + lcq];  // row above
        float aw[4] = {bf2f(ua.x), bf2f(ua.y), bf2f(ua.z), bf2f(ua.w)};
        ushort4 ub = *(const ushort4*)&xt[( slot   *10 + lrow + 2)*40 + lcq];  // row below
        float bw[4] = {bf2f(ub.x), bf2f(ub.y), bf2f(ub.z), bf2f(ub.w)};
        float al  = __shfl_up(aw[3], 1);
        float ar  = __shfl_down(aw[0], 1);
        float ol  = __shfl_up(o0[3], 1);
        float orr = __shfl_down(o0[0], 1);
        float bl  = __shfl_up(bw[3], 1);
        float br  = __shfl_down(bw[0], 1);
        float wlo_c = g_wlo[b*CC + c];
        float whi_c = g_whi[b*CC + c];
        float res[4];
        #pragma unroll
        for (int i = 0; i < 4; ++i) {
            float ul = (i == 0) ? al  : aw[i-1];
            float uu = aw[i];
            float ur = (i == 3) ? ar  : aw[i+1];
            float ll = (i == 0) ? ol  : o0[i-1];
            float rr = (i == 3) ? orr : o0[i+1];
            float dl = (i == 0) ? bl  : bw[i-1];
            float dd = bw[i];
            float dr = (i == 3) ? br  : bw[i+1];
            float hs = wq[i][0]*ul + wq[i][1]*uu + wq[i][2]*ur
                     + wq[i][3]*ll + wq[i][4]*rr
                     + wq[i][5]*dl + wq[i][6]*dd + wq[i][7]*dr;
            float hp = wlo_c*pm1[i] + whi_c*p1[i];
            float h  = hs + hp;
            float el = (h > 0.f) ? h : expm1f(h);
            res[i] = o0[i] + gama*(el - o0[i]);       // (1-g)x + g*h'
        }
        *(float4*)(ob + (size_t)c*NN + pbase) = make_float4(res[0], res[1], res[2], res[3]);
        #pragma unroll
        for (int i = 0; i < 4; ++i) { pm1[i] = o0[i]; o0[i] = p1[i]; }
    }
}

extern "C" void kernel_launch(void* const* d_in, const int* in_sizes, int n_in,
                              void* d_out, int out_size, void* d_ws, size_t ws_size,
                              hipStream_t stream) {
    const float* x    = (const float*)d_in[0];
    const float* wa   = (const float*)d_in[1];
    const float* ga   = (const float*)d_in[2];
    const float* ba   = (const float*)d_in[3];
    const float* ma   = (const float*)d_in[4];
    const float* va   = (const float*)d_in[5];
    const float* wsig = (const float*)d_in[6];
    const float* gs   = (const float*)d_in[7];
    const float* bs   = (const float*)d_in[8];
    const float* ms   = (const float*)d_in[9];
    const float* vs   = (const float*)d_in[10];
    const float* gama = (const float*)d_in[11];
    float* out = (float*)d_out;

    hipLaunchKernelGGL(k_gemm, dim3(512),      dim3(256), 0, stream,
                       x, wa, ga, va, ba, ma, wsig, gs, vs, bs, ms);
    hipLaunchKernelGGL(k_wc,   dim3(WBLK+BB),  dim3(256), 0, stream);
    hipLaunchKernelGGL(k_main, dim3(2048),     dim3(256), 0, stream, x, gama, out);
}